// Round 6
// baseline (198.806 us; speedup 1.0000x reference)
//
#include <hip/hip_runtime.h>

typedef __attribute__((ext_vector_type(4))) float f32x4;
typedef __attribute__((ext_vector_type(8))) short bf16x8;

#define LOG2E 1.44269504088896340736f
// lgkm-only barrier: LDS h-exchange must drain, but global stores/loads stay in flight
#define BAR_LGKM() asm volatile("s_waitcnt lgkmcnt(0)\n\ts_barrier" ::: "memory")

__device__ __forceinline__ float bcf(unsigned u){ union{unsigned u;float f;}v; v.u=u; return v.f; }
__device__ __forceinline__ unsigned pkbf(float a, float b){
    unsigned w; asm("v_cvt_pk_bf16_f32 %0, %1, %2" : "=v"(w) : "v"(a), "v"(b)); return w;
}
__device__ __forceinline__ float ex2(float x){ return __builtin_amdgcn_exp2f(x); }
__device__ __forceinline__ float rcp_(float x){ return __builtin_amdgcn_rcpf(x); }

#define MFMA(a,b,c) __builtin_amdgcn_mfma_f32_16x16x32_bf16(a,b,c,0,0,0)

union FragU { unsigned w[4]; bf16x8 v; };

// split 8 f32 into hi/lo bf16 fragments
__device__ __forceinline__ void split8(const float* v, bf16x8 &fh, bf16x8 &fl){
    FragU H, L;
#pragma unroll
    for (int i=0;i<4;i++){
        unsigned w = pkbf(v[2*i], v[2*i+1]);
        H.w[i] = w;
        float ra = v[2*i]   - bcf(w<<16);
        float rb = v[2*i+1] - bcf(w & 0xffff0000u);
        L.w[i] = pkbf(ra, rb);
    }
    fh = H.v; fl = L.v;
}

// B-frag for packed x-MFMA: k = [xh(0-3), xl(4-7) | xh(8-11), 1@12, 1@13 | 0 | 0]
__device__ __forceinline__ void build_bx(const float4& x, int hi, FragU& B){
    unsigned w0 = pkbf(x.x, x.y), w1 = pkbf(x.z, x.w);
    float r0 = x.x - bcf(w0<<16), r1 = x.y - bcf(w0 & 0xffff0000u);
    float r2 = x.z - bcf(w1<<16), r3 = x.w - bcf(w1 & 0xffff0000u);
    unsigned l0 = pkbf(r0,r1), l1 = pkbf(r2,r3);
    const bool h01 = (hi < 2);
    B.w[0] = h01 ? w0 : 0u;
    B.w[1] = h01 ? w1 : 0u;
    B.w[2] = (hi==0) ? l0 : (hi==1 ? 0x3f803f80u : 0u);
    B.w[3] = (hi==0) ? l1 : 0u;
}

// i16x8 -> exact hi/lo bf16 fragments
__device__ __forceinline__ void dec_q(const uint4& xw, FragU& Xh, FragU& Xl){
    float xv[8];
    xv[0]=(float)(short)(xw.x & 0xffffu); xv[1]=(float)((int)xw.x >> 16);
    xv[2]=(float)(short)(xw.y & 0xffffu); xv[3]=(float)((int)xw.y >> 16);
    xv[4]=(float)(short)(xw.z & 0xffffu); xv[5]=(float)((int)xw.z >> 16);
    xv[6]=(float)(short)(xw.w & 0xffffu); xv[7]=(float)((int)xw.w >> 16);
    split8(xv, Xh.v, Xl.v);
}

// write one h value as bf16 hi/lo halves at [col][j] (pitch 40 halves)
__device__ __forceinline__ void put_h1(unsigned (*hb)[16][20], int col, int j, float h){
    unsigned wpk = pkbf(h, 0.0f);
    float rr = h - bcf(wpk<<16);
    unsigned lw = pkbf(rr, 0.0f);
    ((unsigned short*)hb[0])[col*40 + j] = (unsigned short)wpk;
    ((unsigned short*)hb[1])[col*40 + j] = (unsigned short)lw;
}

// 8 waves x j-quartet; 16 batch per block; lgkm-only in-loop barriers
__global__ __launch_bounds__(512, 4) void lstm2_o(
    const float* __restrict__ xin,   // [8192,64,4]
    const float* __restrict__ sfc,   // [8192,5]
    const float* __restrict__ w_sfc1, const float* __restrict__ b_sfc1,
    const float* __restrict__ w_sfc2, const float* __restrict__ b_sfc2,
    const float* __restrict__ w_ih1, const float* __restrict__ w_hh1,
    const float* __restrict__ b_ih1, const float* __restrict__ b_hh1,
    const float* __restrict__ w_ih2, const float* __restrict__ w_hh2,
    const float* __restrict__ b_ih2, const float* __restrict__ b_hh2,
    const float* __restrict__ w_out, const float* __restrict__ b_out,
    float* __restrict__ outp,        // [8192,64,1]
    unsigned* __restrict__ ws)       // out1 history: 16384 uints per block
{
    __shared__ __align__(16) unsigned hbuf[2][2][16][20]; // [par][hi/lo][b][20w]
    __shared__ float ybuf[8][64][16];

    const int tid  = threadIdx.x;
    const int w    = tid >> 6;          // wave -> j-quartet [4w, 4w+4)
    const int lane = tid & 63;
    const int col  = lane & 15;         // batch col (A-row on weight side)
    const int hi   = lane >> 4;         // k-quad; D row-quad -> local j
    const int B0   = blockIdx.x * 16;
    unsigned* wsb  = ws + blockIdx.x * 16384;

    const int jl = col >> 2, g = col & 3;            // A-row r=col -> (jl, gate)
    const float sc = (g == 2) ? (2.0f*LOG2E) : (-LOG2E);
    const int j    = 4*w + hi;                        // this lane's hidden unit
    const int grow = g*32 + 4*w + jl;                 // weight row for A side

    // ---------------- layer-1 A-frags -----------------------------------------
    bf16x8 Whh_h, Whh_l, WxA;
    {
        float wvv[8];
        float4 wa = *(const float4*)(w_hh1 + grow*32 + 8*hi);
        float4 wb = *(const float4*)(w_hh1 + grow*32 + 8*hi + 4);
        wvv[0]=wa.x*sc; wvv[1]=wa.y*sc; wvv[2]=wa.z*sc; wvv[3]=wa.w*sc;
        wvv[4]=wb.x*sc; wvv[5]=wb.y*sc; wvv[6]=wb.z*sc; wvv[7]=wb.w*sc;
        split8(wvv, Whh_h, Whh_l);
        float4 wi = *(const float4*)(w_ih1 + grow*4);
        float wh0=wi.x*sc, wh1=wi.y*sc, wh2=wi.z*sc, wh3=wi.w*sc;
        unsigned xw0 = pkbf(wh0,wh1), xw1 = pkbf(wh2,wh3);
        float wl0 = wh0-bcf(xw0<<16), wl1 = wh1-bcf(xw0 & 0xffff0000u);
        float wl2 = wh2-bcf(xw1<<16), wl3 = wh3-bcf(xw1 & 0xffff0000u);
        unsigned lw0 = pkbf(wl0,wl1), lw1 = pkbf(wl2,wl3);
        float bias = (b_ih1[grow] + b_hh1[grow])*sc;
        unsigned bh = pkbf(bias, 0.0f);
        float blo = bias - bcf(bh<<16);
        unsigned bword = pkbf(bias, blo);
        FragU A;
        if (hi==0){ A.w[0]=xw0; A.w[1]=xw1; A.w[2]=xw0; A.w[3]=xw1; }
        else if (hi==1){ A.w[0]=lw0; A.w[1]=lw1; A.w[2]=bword; A.w[3]=0u; }
        else { A.w[0]=0u; A.w[1]=0u; A.w[2]=0u; A.w[3]=0u; }
        WxA = A.v;
    }
    // ---------------- layer-2 A-frags -----------------------------------------
    bf16x8 W2h_h, W2h_l, W2x_h, W2x_l;
    {
        float wvv[8];
        {
            float4 wa = *(const float4*)(w_hh2 + grow*32 + 8*hi);
            float4 wb = *(const float4*)(w_hh2 + grow*32 + 8*hi + 4);
            wvv[0]=wa.x*sc; wvv[1]=wa.y*sc; wvv[2]=wa.z*sc; wvv[3]=wa.w*sc;
            wvv[4]=wb.x*sc; wvv[5]=wb.y*sc; wvv[6]=wb.z*sc; wvv[7]=wb.w*sc;
        }
        split8(wvv, W2h_h, W2h_l);
        {
            const float scx = sc * (1.0f/32767.0f);
            float4 wa = *(const float4*)(w_ih2 + grow*32 + 8*hi);
            float4 wb = *(const float4*)(w_ih2 + grow*32 + 8*hi + 4);
            wvv[0]=wa.x*scx; wvv[1]=wa.y*scx; wvv[2]=wa.z*scx; wvv[3]=wa.w*scx;
            wvv[4]=wb.x*scx; wvv[5]=wb.y*scx; wvv[6]=wb.z*scx; wvv[7]=wb.w*scx;
        }
        split8(wvv, W2x_h, W2x_l);
    }
    float bia[4], woutj;
#pragma unroll
    for (int p=0;p<4;p++){
        const float s = (p==2) ? (2.0f*LOG2E) : (-LOG2E);
        bia[p] = (b_ih2[p*32+j] + b_hh2[p*32+j]) * s;
    }
    woutj = w_out[j];

    // ---------------- surface MLP -> h0, cs0 ----------------------------------
    float cs, hv;
    {
        const float* sp = sfc + (B0 + col)*5;
        const float s0=sp[0], s1=sp[1], s2=sp[2], s3=sp[3], s4=sp[4];
        float a1 = b_sfc1[j] + s0*w_sfc1[j*5+0] + s1*w_sfc1[j*5+1]
                 + s2*w_sfc1[j*5+2] + s3*w_sfc1[j*5+3] + s4*w_sfc1[j*5+4];
        float a2 = b_sfc2[j] + s0*w_sfc2[j*5+0] + s1*w_sfc2[j*5+1]
                 + s2*w_sfc2[j*5+2] + s3*w_sfc2[j*5+3] + s4*w_sfc2[j*5+4];
        hv = 1.0f - 2.0f*rcp_(ex2((2.0f*LOG2E)*a1)+1.0f);
        cs = (2.0f*LOG2E)*(1.0f - 2.0f*rcp_(ex2((2.0f*LOG2E)*a2)+1.0f));
    }
    put_h1(hbuf[0], col, j, hv);
    __syncthreads();

    // ---------------- phase 1: layer-1 LSTM, reversed time --------------------
    int par = 0;
    FragU Bx;
    {
        float4 x0 = *(const float4*)(xin + ((B0 + col)*64 + 63)*4);
        build_bx(x0, hi, Bx);
    }
#pragma unroll 1
    for (int t=63; t>=0; --t){
        bf16x8 Hh = *(const bf16x8*)&hbuf[par][0][col][4*hi];
        bf16x8 Hl = *(const bf16x8*)&hbuf[par][1][col][4*hi];
        f32x4 a = {0.f,0.f,0.f,0.f}, b2 = {0.f,0.f,0.f,0.f};
        a  = MFMA(WxA,   Bx.v, a);      // x-proj + bias (packed k), no LDS dep
        b2 = MFMA(Whh_h, Hl,   b2);
        a  = MFMA(Whh_h, Hh,   a);
        b2 = MFMA(Whh_l, Hh,   b2);
        if (t){
            float4 xn = *(const float4*)(xin + ((B0 + col)*64 + (t-1))*4);
            build_bx(xn, hi, Bx);
        }
        f32x4 acc = a + b2;
        float si = rcp_(1.0f+ex2(acc[0]));
        float sf = rcp_(1.0f+ex2(acc[1]));
        float tg = 1.0f - 2.0f*rcp_(ex2(acc[2])+1.0f);
        float so = rcp_(1.0f+ex2(acc[3]));
        cs = fmaf(sf, cs, ((2.0f*LOG2E)*si)*tg);
        float tc = 1.0f - 2.0f*rcp_(ex2(cs)+1.0f);
        hv = so*tc;
        put_h1(hbuf[par^1], col, j, hv);
        int q = __float2int_rn(hv*32767.0f);
        int e = __shfl_xor(q, 16, 64);          // pair j with j^1 (hi bit0)
        if (!(hi & 1)){
            unsigned val = ((unsigned)q & 0xffffu) | ((unsigned)e << 16);
            wsb[(t*16 + col)*16 + 2*w + (hi>>1)] = val;   // store floats free across barrier
        }
        BAR_LGKM();
        par ^= 1;
    }

    // ---------------- phase 1 -> 2 transition ---------------------------------
    cs = 0.0f;
    put_h1(hbuf[par], col, j, 0.0f);
    __syncthreads();                 // full drain: out1 stores visible to all waves
    FragU Xh, Xl;
    {
        const uint4 xw = *(const uint4*)&wsb[(0*16 + col)*16 + 4*hi];
        dec_q(xw, Xh, Xl);
    }

    // ---------------- phase 2: layer-2 LSTM + fused output --------------------
#pragma unroll 1
    for (int t=0; t<64; ++t){
        bf16x8 Hh = *(const bf16x8*)&hbuf[par][0][col][4*hi];
        bf16x8 Hl = *(const bf16x8*)&hbuf[par][1][col][4*hi];
        f32x4 a = {0.f,0.f,0.f,0.f}, b2 = {0.f,0.f,0.f,0.f};
        a  = MFMA(W2x_h, Xh.v, a);      // x-chain: no LDS dep, starts immediately
        b2 = MFMA(W2h_h, Hh,   b2);
        a  = MFMA(W2x_h, Xl.v, a);
        b2 = MFMA(W2h_h, Hl,   b2);
        a  = MFMA(W2x_l, Xh.v, a);
        b2 = MFMA(W2h_l, Hh,   b2);
        const int tn = (t < 63) ? t+1 : 63;
        const uint4 xw = *(const uint4*)&wsb[(tn*16 + col)*16 + 4*hi];
        f32x4 acc = a + b2;
        float si = rcp_(1.0f+ex2(acc[0]+bia[0]));
        float sf = rcp_(1.0f+ex2(acc[1]+bia[1]));
        float tg = 1.0f - 2.0f*rcp_(ex2(acc[2]+bia[2])+1.0f);
        float so = rcp_(1.0f+ex2(acc[3]+bia[3]));
        cs = fmaf(sf, cs, ((2.0f*LOG2E)*si)*tg);
        float tc = 1.0f - 2.0f*rcp_(ex2(cs)+1.0f);
        hv = so*tc;
        float y = hv * woutj;
        y += __shfl_xor(y, 16, 64);
        y += __shfl_xor(y, 32, 64);
        if (hi == 0) ybuf[w][t][col] = y;
        put_h1(hbuf[par^1], col, j, hv);
        dec_q(xw, Xh, Xl);
        BAR_LGKM();
        par ^= 1;
    }

    // ---------------- epilogue: sum 8 wave partials, coalesced store ----------
    const float bo = b_out[0];
    const int bb = tid >> 5;            // 0..15
    const int t0 = (tid & 31) * 2;      // 0..62
    float s0 = bo, s1 = bo;
#pragma unroll
    for (int u=0; u<8; ++u){ s0 += ybuf[u][t0][bb]; s1 += ybuf[u][t0+1][bb]; }
    *(float2*)(outp + (B0 + bb)*64 + t0) = make_float2(s0, s1);
}

extern "C" void kernel_launch(void* const* d_in, const int* in_sizes, int n_in,
                              void* d_out, int out_size, void* d_ws, size_t ws_size,
                              hipStream_t stream) {
    const float* xin    = (const float*)d_in[0];
    const float* sfc    = (const float*)d_in[1];
    const float* w_sfc1 = (const float*)d_in[2];
    const float* b_sfc1 = (const float*)d_in[3];
    const float* w_sfc2 = (const float*)d_in[4];
    const float* b_sfc2 = (const float*)d_in[5];
    const float* w_ih1  = (const float*)d_in[6];
    const float* w_hh1  = (const float*)d_in[7];
    const float* b_ih1  = (const float*)d_in[8];
    const float* b_hh1  = (const float*)d_in[9];
    const float* w_ih2  = (const float*)d_in[10];
    const float* w_hh2  = (const float*)d_in[11];
    const float* b_ih2  = (const float*)d_in[12];
    const float* b_hh2  = (const float*)d_in[13];
    const float* w_out  = (const float*)d_in[14];
    const float* b_out  = (const float*)d_in[15];
    float* out = (float*)d_out;

    hipLaunchKernelGGL(lstm2_o, dim3(512), dim3(512), 0, stream,
                       xin, sfc, w_sfc1, b_sfc1, w_sfc2, b_sfc2,
                       w_ih1, w_hh1, b_ih1, b_hh1,
                       w_ih2, w_hh2, b_ih2, b_hh2,
                       w_out, b_out, out, (unsigned*)d_ws);
}